// Round 12
// baseline (230.320 us; speedup 1.0000x reference)
//
#include <hip/hip_runtime.h>
#include <hip/hip_cooperative_groups.h>
#include <math.h>

namespace cg = cooperative_groups;

#define NB 2
#define SEQ 2048
#define HD 1024
#define NH 8
#define DH 128
#define HALF 64

typedef __bf16 bf16_t;
typedef __attribute__((ext_vector_type(8))) __bf16 bf16x8;
typedef __attribute__((ext_vector_type(4))) __bf16 bf16x4;
typedef __attribute__((ext_vector_type(4))) float f32x4;

typedef __attribute__((address_space(1))) void gvoid;
typedef __attribute__((address_space(3))) void lvoid;

__device__ __forceinline__ void gld16(const bf16_t* g, bf16_t* l) {
  __builtin_amdgcn_global_load_lds((gvoid*)g, (lvoid*)l, 16, 0, 0);
}

__device__ __forceinline__ float head_l2g(int hh) {
  double ga = log(1.0/32.0), gbb = log(1.0/512.0);
  float gamma = (float)(1.0 - exp(ga + (double)hh * (gbb - ga) / 7.0));
  return log2f(gamma);
}

// shared transpose+cast body (stride-parameterized)
__device__ __forceinline__ void wsplit_body(
    const float* in, bf16_t* oh, int M, int N,
    int bx, int by, int z, float (*tile)[65], int nthr, int t) {
  in += (size_t)z * M * N; oh += (size_t)z * M * N;
  int r0 = by * 64, c0 = bx * 64;
  for (int idx = t; idx < 1024; idx += nthr) {
    int r = idx >> 4, c4 = (idx & 15) * 4;
    float4 v = *(const float4*)(in + (size_t)(r0 + r) * N + c0 + c4);
    *(float4*)&tile[r][c4] = v;
  }
  __syncthreads();
  for (int idx = t; idx < 1024; idx += nthr) {
    int c = idx >> 4, r4 = (idx & 15) * 4;
    bf16x4 h;
    #pragma unroll
    for (int j = 0; j < 4; ++j)
      h[j] = (bf16_t)tile[r4 + j][c];
    *(bf16x4*)(oh + (size_t)(c0 + c) * M + r0 + r4) = h;
  }
}

// =====================================================================
// k_fused (COOPERATIVE, grid 256 x 512 thr, 144KB LDS, 1 block/CU):
//   phase 0: Wg/Wo transpose tiles (2 per block)
//   phase 1: QKV projection from fp32 W (in-block W^T stage) + on-the-fly
//            xpos; Q->Qsh, K->Ksh + decayed K^T->KTd, V->Vsh (all LDS);
//            Xh store; delta MFMA -> DSt (global)
//   grid.sync()
//   phase 2: chunk-scan (DSt) -> Slds(=KTd); cross Q·S^T; intra full-chunk
//            retention (Ksh/Vsh/Ph=Qsh); fused groupnorm -> Yn
// =====================================================================
__global__ __launch_bounds__(512, 1) void k_fused(
    const float* __restrict__ X,
    const float* __restrict__ Wq, const float* __restrict__ Wk,
    const float* __restrict__ Wv, const float* __restrict__ Wg,
    const float* __restrict__ Wo,
    const float* __restrict__ gw, const float* __restrict__ gb,
    bf16_t* __restrict__ Xhg, bf16_t* __restrict__ DSt,
    bf16_t* __restrict__ Yn, bf16_t* __restrict__ Wgt,
    bf16_t* __restrict__ Wot) {
  __shared__ bf16_t Wsh[64][128];      // 16KB  W^T half-tile
  __shared__ bf16_t KTd[128][128];     // 32KB  decayed K^T -> Slds (phase 2)
  __shared__ bf16_t Vsh[128][128];     // 32KB  V^T [dv][tau] (persists)
  __shared__ bf16_t Ksh[128][128];     // 32KB  K rows [tau][dh] (persists)
  __shared__ bf16_t Qsh[128][128];     // 32KB  tile / Q rows -> Ph (phase 2)
  int t = threadIdx.x;
  int lane = t & 63, w = t >> 6;       // 8 waves
  int lr = lane & 15, lg = lane >> 4;
  int bid = blockIdx.x;
  int c = bid & 15, bh = bid >> 4, hh = bh & 7, b = bh >> 3;
  int s0 = c * 128;
  float l2g = head_l2g(hh);

  // ---- phase 0: Wg/Wo transposes, tile buffer aliases Qsh ----
  {
    float (*tile)[65] = (float(*)[65])&Qsh[0][0];
    #pragma unroll
    for (int k = 0; k < 2; ++k) {
      int i = bid * 2 + k;             // 512 tiles: 2 x (16x16)
      int which = i >> 8, j = i & 255;
      wsplit_body(which ? Wo : Wg, which ? Wot : Wgt, HD, HD,
                  j & 15, j >> 4, 0, tile, 512, t);
      __syncthreads();
    }
  }

  // ---- X fragments + Xh store ----
  bf16x8 xh[4];
  {
    const float* xp = X + ((size_t)(b*SEQ + s0 + 16*w + lr)) * HD + hh*DH + 8*lg;
    #pragma unroll
    for (int ks = 0; ks < 4; ++ks) {
      float4 u = *(const float4*)(xp + 32*ks);
      float4 v = *(const float4*)(xp + 32*ks + 4);
      float fv[8] = {u.x,u.y,u.z,u.w,v.x,v.y,v.z,v.w};
      #pragma unroll
      for (int j = 0; j < 8; ++j) xh[ks][j] = (bf16_t)fv[j];
    }
    bf16_t* xo = Xhg + ((size_t)(b*SEQ + s0 + 16*w + lr)) * HD + hh*DH + 8*lg;
    #pragma unroll
    for (int ks = 0; ks < 4; ++ks)
      *(bf16x8*)(xo + 32*ks) = xh[ks];
  }

  // ---- phase 1: Q/K/V projection (W^T staged in-block from fp32) ----
  const float* Wsrc[3] = {Wq, Wk, Wv};
  for (int which = 0; which < 3; ++which) {
    const float* wp = Wsrc[which] + (size_t)hh * (DH*DH);
    f32x4 yacc[8];
    #pragma unroll
    for (int i = 0; i < 8; ++i) yacc[i] = (f32x4){0.f,0.f,0.f,0.f};
    for (int hf = 0; hf < 2; ++hf) {
      __syncthreads();                 // Wsh free
      for (int idx = t; idx < 2048; idx += 512) {
        int d = idx >> 4;
        int e4 = (idx & 15) * 4 + hf * 64;
        float4 v = *(const float4*)(wp + (size_t)d * DH + e4);
        float fv[4] = {v.x, v.y, v.z, v.w};
        #pragma unroll
        for (int j = 0; j < 4; ++j) {
          int e = e4 + j;
          Wsh[e - hf*64][(((d>>3) ^ (e & 7)) << 3) | (d & 7)] = (bf16_t)fv[j];
        }
      }
      __syncthreads();
      #pragma unroll
      for (int su = 0; su < 4; ++su) {
        int sub = hf*4 + su;
        int el = 16*su + lr;
        #pragma unroll
        for (int ks = 0; ks < 4; ++ks) {
          int ch = (lg + 4*ks) ^ (el & 7);
          bf16x8 bhv = *(const bf16x8*)&Wsh[el][ch*8];
          yacc[sub] = __builtin_amdgcn_mfma_f32_16x16x32_bf16(xh[ks], bhv, yacc[sub], 0, 0, 0);
        }
      }
    }
    // epilogue
    if (which < 2) {
      #pragma unroll
      for (int sub = 0; sub < 8; ++sub) {
        int e = 16*sub + lr;
        int i2 = e >> 1;
        float scale = (2.f*(float)i2 + 51.2f) * (1.f/179.2f);
        float l2s = log2f(scale);
        float invf = exp2f(-13.287712379549449f * (float)i2 * (1.f/64.f));
        #pragma unroll
        for (int reg = 0; reg < 4; ++reg) {
          float v = yacc[sub][reg];
          float p = __shfl_xor(v, 1);
          int tau = 16*w + 4*lg + reg;
          int srow = s0 + tau;
          float sc = exp2f(l2s * (float)srow * (1.f/512.f));
          float ang = (float)srow * invf;
          float sn, cs;
          sincosf(ang, &sn, &cs);
          float scq = (which == 0) ? sc : (1.f/sc);
          float o = v * (cs*scq) + ((e & 1) ? p : -p) * (sn*scq);
          bf16_t ob = (bf16_t)o;
          if (which == 0) {
            Qsh[tau][(((e>>3) ^ (tau&7)) << 3) | (e & 7)] = ob;
          } else {
            Ksh[tau][(((e>>3) ^ (tau&7)) << 3) | (e & 7)] = ob;
            float kd = o * exp2f(l2g * (float)(127 - tau));
            KTd[e][(((tau>>3) ^ (e&7)) << 3) | (tau & 7)] = (bf16_t)kd;
          }
        }
      }
    } else {
      #pragma unroll
      for (int sub = 0; sub < 8; ++sub) {
        int e = 16*sub + lr;
        #pragma unroll
        for (int reg = 0; reg < 4; ++reg) {
          int tau = 16*w + 4*lg + reg;
          Vsh[e][(((tau>>3) ^ (e&7)) << 3) | (tau & 7)] = (bf16_t)yacc[sub][reg];
        }
      }
    }
  }
  __syncthreads();                     // Qsh/Ksh/KTd/Vsh complete

  // ---- delta: Dt[dv][dk] = sum_tau Vsh[dv][tau] * KTd[dk][tau] ----
  {
    f32x4 dacc[8];
    #pragma unroll
    for (int s = 0; s < 8; ++s) dacc[s] = (f32x4){0.f,0.f,0.f,0.f};
    int dv = 16*w + lr;
    #pragma unroll
    for (int ks = 0; ks < 4; ++ks) {
      int ca = (lg + 4*ks) ^ (dv & 7);
      bf16x8 av = *(const bf16x8*)&Vsh[dv][ca*8];
      #pragma unroll
      for (int sub = 0; sub < 8; ++sub) {
        int dk = 16*sub + lr;
        int cb = (lg + 4*ks) ^ (dk & 7);
        bf16x8 bk = *(const bf16x8*)&KTd[dk][cb*8];
        dacc[sub] = __builtin_amdgcn_mfma_f32_16x16x32_bf16(av, bk, dacc[sub], 0, 0, 0);
      }
    }
    size_t obase = ((size_t)bh * 16 + c) * 16384;
    #pragma unroll
    for (int sub = 0; sub < 8; ++sub)
      #pragma unroll
      for (int reg = 0; reg < 4; ++reg) {
        int dvv = 16*w + 4*lg + reg;
        int dk = 16*sub + lr;
        DSt[obase + (size_t)dvv*128 + dk] = (bf16_t)dacc[sub][reg];
      }
  }
  __threadfence();
  cg::this_grid().sync();

  // ================= phase 2 =================
  // Q fragments from Qsh (before Ph overwrites it)
  bf16x8 qh[4];
  {
    int q = 16*w + lr;
    #pragma unroll
    for (int ks = 0; ks < 4; ++ks) {
      int ch = (lg + 4*ks) ^ (q & 7);
      qh[ks] = *(const bf16x8*)&Qsh[q][ch*8];
    }
  }

  // in-block scan: S_c from raw deltas (KTd reused as Slds)
  {
    float g128 = exp2f(l2g * 128.0f);
    float S0[8] = {}, S1[8] = {}, S2[8] = {}, S3[8] = {};
    const bf16_t* dbase = DSt + ((size_t)bh * 16) * 16384
                        + (size_t)(t >> 2) * 128 + (t & 3) * 32;
    for (int cp = 0; cp < c; ++cp) {
      const bf16_t* dp = dbase + (size_t)cp * 16384;
      bf16x8 d0 = *(const bf16x8*)dp;
      bf16x8 d1 = *(const bf16x8*)(dp + 8);
      bf16x8 d2 = *(const bf16x8*)(dp + 16);
      bf16x8 d3 = *(const bf16x8*)(dp + 24);
      #pragma unroll
      for (int j = 0; j < 8; ++j) {
        S0[j] = g128*S0[j] + (float)d0[j];
        S1[j] = g128*S1[j] + (float)d1[j];
        S2[j] = g128*S2[j] + (float)d2[j];
        S3[j] = g128*S3[j] + (float)d3[j];
      }
    }
    int dv = t >> 2;
    #pragma unroll
    for (int q4 = 0; q4 < 4; ++q4) {
      const float* Sq = (q4 == 0) ? S0 : (q4 == 1) ? S1 : (q4 == 2) ? S2 : S3;
      int ch = ((t & 3) * 4 + q4) ^ (dv & 7);
      bf16x8 s8;
      #pragma unroll
      for (int j = 0; j < 8; ++j) s8[j] = (bf16_t)Sq[j];
      *(bf16x8*)&KTd[dv][ch*8] = s8;
    }
  }
  __syncthreads();   // Slds ready; all qh reads done (Qsh free for Ph)

  // cross: yacc = Q · S^T, scaled by gamma^(q+1)
  f32x4 yacc[8];
  #pragma unroll
  for (int i = 0; i < 8; ++i) yacc[i] = (f32x4){0.f,0.f,0.f,0.f};
  {
    #pragma unroll
    for (int sub = 0; sub < 8; ++sub) {
      int dv = 16*sub + lr;
      #pragma unroll
      for (int ks = 0; ks < 4; ++ks) {
        int ch = (lg + 4*ks) ^ (dv & 7);
        bf16x8 b8 = *(const bf16x8*)&KTd[dv][ch*8];
        yacc[sub] = __builtin_amdgcn_mfma_f32_16x16x32_bf16(qh[ks], b8, yacc[sub], 0, 0, 0);
      }
    }
    float rowc[4];
    #pragma unroll
    for (int reg = 0; reg < 4; ++reg)
      rowc[reg] = exp2f(l2g * (float)(16*w + 4*lg + reg + 1));
    #pragma unroll
    for (int sub = 0; sub < 8; ++sub)
      #pragma unroll
      for (int reg = 0; reg < 4; ++reg)
        yacc[sub][reg] *= rowc[reg];
  }

  // intra: single pass over full 128-key chunk (Ksh, Ph=Qsh, Vsh)
  {
    float colf = exp2f(-l2g * (float)lr);
    float rowf[4];
    #pragma unroll
    for (int reg = 0; reg < 4; ++reg)
      rowf[reg] = exp2f(l2g * (float)(16*w + 4*lg + reg));
    #pragma unroll
    for (int ts = 0; ts < 8; ++ts) {
      f32x4 sacc = (f32x4){0.f,0.f,0.f,0.f};
      int trow = 16*ts + lr;
      #pragma unroll
      for (int ks = 0; ks < 4; ++ks) {
        int kbs = (4*ks + lg) ^ (trow & 7);
        bf16x8 kh8 = *(const bf16x8*)&Ksh[trow][kbs*8];
        sacc = __builtin_amdgcn_mfma_f32_16x16x32_bf16(qh[ks], kh8, sacc, 0, 0, 0);
      }
      float cf = colf * exp2f(-l2g * (float)(16*ts));
      #pragma unroll
      for (int reg = 0; reg < 4; ++reg) {
        int qloc = 16*w + 4*lg + reg;
        int diff = qloc - trow;
        float p = (diff >= 0) ? sacc[reg] * (rowf[reg] * cf) : 0.0f;
        Qsh[qloc][(((trow>>3) ^ (qloc&7)) << 3) | (trow & 7)] = (bf16_t)p;
      }
    }
    #pragma unroll
    for (int ks = 0; ks < 4; ++ks) {
      int prow = 16*w + lr;
      int pcb = (4*ks + lg) ^ (prow & 7);
      bf16x8 pah = *(const bf16x8*)&Qsh[prow][pcb*8];
      #pragma unroll
      for (int sub = 0; sub < 8; ++sub) {
        int dv = 16*sub + lr;
        int vcb = (4*ks + lg) ^ (dv & 7);
        bf16x8 vh8 = *(const bf16x8*)&Vsh[dv][vcb*8];
        yacc[sub] = __builtin_amdgcn_mfma_f32_16x16x32_bf16(pah, vh8, yacc[sub], 0, 0, 0);
      }
    }
  }

  // fused groupnorm (bf16 out)
  float s1v[4] = {0.f,0.f,0.f,0.f}, s2v[4] = {0.f,0.f,0.f,0.f};
  #pragma unroll
  for (int sub = 0; sub < 8; ++sub)
    #pragma unroll
    for (int reg = 0; reg < 4; ++reg) {
      float v = yacc[sub][reg];
      s1v[reg] += v;
      s2v[reg] += v * v;
    }
  #pragma unroll
  for (int off = 8; off; off >>= 1)
    #pragma unroll
    for (int reg = 0; reg < 4; ++reg) {
      s1v[reg] += __shfl_xor(s1v[reg], off);
      s2v[reg] += __shfl_xor(s2v[reg], off);
    }
  float gwv[8], gbv[8];
  #pragma unroll
  for (int sub = 0; sub < 8; ++sub) {
    gwv[sub] = gw[hh*DH + 16*sub + lr];
    gbv[sub] = gb[hh*DH + 16*sub + lr];
  }
  #pragma unroll
  for (int reg = 0; reg < 4; ++reg) {
    float mean = s1v[reg] * (1.0f/128.0f);
    float var = s2v[reg] * (1.0f/128.0f) - mean*mean;
    float inv = rsqrtf(var + 1e-5f);
    int srow = s0 + 16*w + 4*lg + reg;
    bf16_t* op = Yn + (size_t)(b*SEQ + srow) * HD + hh*DH;
    #pragma unroll
    for (int sub = 0; sub < 8; ++sub)
      op[16*sub + lr] = (bf16_t)((yacc[sub][reg] - mean) * inv * gwv[sub] + gbv[sub]);
  }
}

// ---------------- plain-bf16 MFMA GEMM, 64x128 tile, 2 blocks/CU -----------
__global__ __launch_bounds__(256, 2) void k_gemm(
    const bf16_t* __restrict__ Ag, const bf16_t* __restrict__ Bg,
    const bf16_t* __restrict__ E,
    bf16_t* __restrict__ Oh, float* __restrict__ Of, int mode) {
  __shared__ bf16_t SA[2][64][64];
  __shared__ bf16_t SBB[2][128][64];
  int t = threadIdx.x;
  int lane = t & 63, w = t >> 6;          // 4 waves
  int lr = lane & 15, lg = lane >> 4;
  int wr = w >> 1, wc = w & 1;
  int bid = blockIdx.x;                   // 512 blocks
  int xcd = bid & 7, local = bid >> 3;
  int mp = xcd * 8 + (local >> 3);
  int np = local & 7;
  int m0 = mp * 64, n0 = np * 128;

  const bf16_t* As = Ag + (size_t)m0 * HD;
  const bf16_t* Bs = Bg + (size_t)n0 * HD;

  f32x4 acc[2][4];
  #pragma unroll
  for (int i = 0; i < 2; ++i)
    #pragma unroll
    for (int j = 0; j < 4; ++j) acc[i][j] = (f32x4){0.f,0.f,0.f,0.f};

  int srow = lane >> 3, sch = lane & 7;

  {
    #pragma unroll
    for (int i = 0; i < 2; ++i) {
      int row = w*16 + i*8 + srow;
      int kc = (sch ^ (row & 7)) * 8;
      gld16(As + (size_t)row*HD + kc, &SA[0][w*16 + i*8][0]);
    }
    #pragma unroll
    for (int i = 0; i < 4; ++i) {
      int row = w*32 + i*8 + srow;
      int kc = (sch ^ (row & 7)) * 8;
      gld16(Bs + (size_t)row*HD + kc, &SBB[0][w*32 + i*8][0]);
    }
  }
  __syncthreads();

  int buf = 0;
  for (int kt = 0; kt < 16; ++kt) {
    if (kt + 1 < 16) {
      int k0 = (kt + 1) * 64;
      #pragma unroll
      for (int i = 0; i < 2; ++i) {
        int row = w*16 + i*8 + srow;
        int kc = (sch ^ (row & 7)) * 8;
        gld16(As + (size_t)row*HD + k0 + kc, &SA[buf^1][w*16 + i*8][0]);
      }
      #pragma unroll
      for (int i = 0; i < 4; ++i) {
        int row = w*32 + i*8 + srow;
        int kc = (sch ^ (row & 7)) * 8;
        gld16(Bs + (size_t)row*HD + k0 + kc, &SBB[buf^1][w*32 + i*8][0]);
      }
    }
    #pragma unroll
    for (int ks = 0; ks < 2; ++ks) {
      bf16x8 a_[2], b_[4];
      #pragma unroll
      for (int mf = 0; mf < 2; ++mf) {
        int row = wr*32 + mf*16 + lr;
        int ch = (lg + 4*ks) ^ (row & 7);
        a_[mf] = *(const bf16x8*)&SA[buf][row][ch*8];
      }
      #pragma unroll
      for (int nf = 0; nf < 4; ++nf) {
        int row = wc*64 + nf*16 + lr;
        int ch = (lg + 4*ks) ^ (row & 7);
        b_[nf] = *(const bf16x8*)&SBB[buf][row][ch*8];
      }
      #pragma unroll
      for (int mf = 0; mf < 2; ++mf)
        #pragma unroll
        for (int nf = 0; nf < 4; ++nf)
          acc[mf][nf] = __builtin_amdgcn_mfma_f32_16x16x32_bf16(a_[mf], b_[nf], acc[mf][nf], 0, 0, 0);
    }
    __syncthreads();
    buf ^= 1;
  }
  #pragma unroll
  for (int mf = 0; mf < 2; ++mf) {
    #pragma unroll
    for (int nf = 0; nf < 4; ++nf) {
      #pragma unroll
      for (int reg = 0; reg < 4; ++reg) {
        int m = m0 + wr*32 + mf*16 + 4*lg + reg;
        int n = n0 + wc*64 + nf*16 + lr;
        float g = acc[mf][nf][reg];
        size_t off = (size_t)m * HD + n;
        if (mode == 1) {
          float sg = 1.0f / (1.0f + expf(-g));
          Oh[off] = (bf16_t)(g * sg * (float)E[off]);
        } else {
          Of[off] = g;
        }
      }
    }
  }
}

extern "C" void kernel_launch(void* const* d_in, const int* in_sizes, int n_in,
                              void* d_out, int out_size, void* d_ws, size_t ws_size,
                              hipStream_t stream) {
  const float* X  = (const float*)d_in[0];
  const float* Wq = (const float*)d_in[1];
  const float* Wk = (const float*)d_in[2];
  const float* Wv = (const float*)d_in[3];
  const float* Wg = (const float*)d_in[4];
  const float* Wo = (const float*)d_in[5];
  const float* gw = (const float*)d_in[6];
  const float* gb = (const float*)d_in[7];
  float* out = (float*)d_out;
  bf16_t* ws = (bf16_t*)d_ws;

  // ws (bf16 elems): Xh 4.2M | Yn 4.2M | DSt 4.2M | Wgt 1M | Wot 1M | A2 4.2M
  bf16_t* Xh  = ws;
  bf16_t* Yn  = Xh + 4194304;
  bf16_t* DSt = Yn + 4194304;
  bf16_t* Wgt = DSt + 4194304;
  bf16_t* Wot = Wgt + 1048576;
  bf16_t* A2  = Wot + 1048576;

  void* args[] = {
    (void*)&X, (void*)&Wq, (void*)&Wk, (void*)&Wv, (void*)&Wg, (void*)&Wo,
    (void*)&gw, (void*)&gb, (void*)&Xh, (void*)&DSt, (void*)&Yn,
    (void*)&Wgt, (void*)&Wot };
  hipLaunchCooperativeKernel((const void*)k_fused, dim3(256), dim3(512),
                             args, 0, stream);
  k_gemm<<<dim3(512), dim3(256), 0, stream>>>(Xh, Wgt, Yn, A2, nullptr, 1);
  k_gemm<<<dim3(512), dim3(256), 0, stream>>>(A2, Wot, nullptr, nullptr, out, 0);
}

// Round 13
// 95.301 us; speedup vs baseline: 2.4168x; 2.4168x over previous
//
#include <hip/hip_runtime.h>
#include <math.h>

#define NB 2
#define SEQ 2048
#define HD 1024
#define NH 8
#define DH 128
#define HALF 64

typedef __bf16 bf16_t;
typedef __attribute__((ext_vector_type(8))) __bf16 bf16x8;
typedef __attribute__((ext_vector_type(4))) __bf16 bf16x4;
typedef __attribute__((ext_vector_type(4))) float f32x4;

typedef __attribute__((address_space(1))) void gvoid;
typedef __attribute__((address_space(3))) void lvoid;

__device__ __forceinline__ void gld16(const bf16_t* g, bf16_t* l) {
  __builtin_amdgcn_global_load_lds((gvoid*)g, (lvoid*)l, 16, 0, 0);
}

__device__ __forceinline__ float head_l2g(int hh) {
  double ga = log(1.0/32.0), gbb = log(1.0/512.0);
  float gamma = (float)(1.0 - exp(ga + (double)hh * (gbb - ga) / 7.0));
  return log2f(gamma);
}

// shared transpose+cast body (stride-parameterized)
__device__ __forceinline__ void wsplit_body(
    const float* in, bf16_t* oh, int M, int N,
    int bx, int by, int z, float (*tile)[65], int nthr, int t) {
  in += (size_t)z * M * N; oh += (size_t)z * M * N;
  int r0 = by * 64, c0 = bx * 64;
  for (int idx = t; idx < 1024; idx += nthr) {
    int r = idx >> 4, c4 = (idx & 15) * 4;
    float4 v = *(const float4*)(in + (size_t)(r0 + r) * N + c0 + c4);
    *(float4*)&tile[r][c4] = v;
  }
  __syncthreads();
  for (int idx = t; idx < 1024; idx += nthr) {
    int c = idx >> 4, r4 = (idx & 15) * 4;
    bf16x4 h;
    #pragma unroll
    for (int j = 0; j < 4; ++j)
      h[j] = (bf16_t)tile[r4 + j][c];
    *(bf16x4*)(oh + (size_t)(c0 + c) * M + r0 + r4) = h;
  }
}

// ---------------- prep: xpos tables + QKV weight transposes ----------------
__global__ __launch_bounds__(256) void k_prep(
    const float* __restrict__ Wq, const float* __restrict__ Wk,
    const float* __restrict__ Wv,
    float* __restrict__ tabs, bf16_t* __restrict__ Wqt,
    bf16_t* __restrict__ Wkt, bf16_t* __restrict__ Wvt) {
  __shared__ float tile[64][65];
  int b = blockIdx.x;
  if (b < 512) {
    int idx = b * 256 + threadIdx.x;
    int s = idx >> 6, i = idx & 63;
    float dd = (float)DH;
    float scale = (2.0f * (float)i + 0.4f * dd) / (1.4f * dd);
    float sc = expf(logf(scale) * ((float)s / 512.0f));
    float inv_freq = expf(-logf(10000.0f) * ((float)i / (float)HALF));
    float ang = (float)s * inv_freq;
    float sn, cs;
    sincosf(ang, &sn, &cs);
    float rsc = 1.0f / sc;
    tabs[idx]               = sn * sc;
    tabs[SEQ*HALF + idx]    = cs * sc;
    tabs[2*SEQ*HALF + idx]  = sn * rsc;
    tabs[3*SEQ*HALF + idx]  = cs * rsc;
  } else {
    int i = b - 512;               // 96 blocks: 3 x (2x2x8)
    int which = i >> 5;
    int j = i & 31;
    const float* in = (which == 0) ? Wq : (which == 1) ? Wk : Wv;
    bf16_t* oh = (which == 0) ? Wqt : (which == 1) ? Wkt : Wvt;
    wsplit_body(in, oh, DH, DH, j & 1, (j >> 1) & 1, j >> 2, tile,
                256, threadIdx.x);
  }
}

// ---------------- fused QKV projection + xpos + per-chunk delta ------------
// grid (16 chunks, 8 heads, 2 batch), 512 thr, 96KB LDS.
__global__ __launch_bounds__(512, 1) void k_qkvd(
    const float* __restrict__ X, const float* __restrict__ tabs,
    const bf16_t* __restrict__ Wqt, const bf16_t* __restrict__ Wkt,
    const bf16_t* __restrict__ Wvt,
    bf16_t* __restrict__ Qo, bf16_t* __restrict__ Ko,
    bf16_t* __restrict__ VTo, bf16_t* __restrict__ Xhg,
    bf16_t* __restrict__ DSt) {
  __shared__ bf16_t Wsh[128][128];     // W^T tile (per weight, reused)
  __shared__ bf16_t KT[128][128];      // [dk][tau], chunk-swz (post-xpos K)
  __shared__ bf16_t Vd[128][128];      // [dv][tau], chunk-swz (decayed V)
  int t = threadIdx.x;
  int lane = t & 63, w = t >> 6;       // 8 waves
  int lr = lane & 15, lg = lane >> 4;
  int c = blockIdx.x, hh = blockIdx.y, b = blockIdx.z;
  int s0 = c * 128;
  size_t bh = (size_t)(b*NH + hh);
  float l2g = head_l2g(hh);

  bf16x8 xh[4];
  {
    const float* xp = X + ((size_t)(b*SEQ + s0 + 16*w + lr)) * HD + hh*DH + 8*lg;
    #pragma unroll
    for (int ks = 0; ks < 4; ++ks) {
      float4 u = *(const float4*)(xp + 32*ks);
      float4 v = *(const float4*)(xp + 32*ks + 4);
      float fv[8] = {u.x,u.y,u.z,u.w,v.x,v.y,v.z,v.w};
      #pragma unroll
      for (int j = 0; j < 8; ++j) xh[ks][j] = (bf16_t)fv[j];
    }
  }
  {
    bf16_t* xo = Xhg + ((size_t)(b*SEQ + s0 + 16*w + lr)) * HD + hh*DH + 8*lg;
    #pragma unroll
    for (int ks = 0; ks < 4; ++ks)
      *(bf16x8*)(xo + 32*ks) = xh[ks];
  }

  const bf16_t* Wp[3] = {Wqt, Wkt, Wvt};

  for (int which = 0; which < 3; ++which) {
    const bf16_t* wp = Wp[which] + (size_t)hh * (DH*DH);
    __syncthreads();                    // Wsh free (prev pass done)
    // async stage W^T: wave w rows [w*16, w*16+16), pre-swizzled source
    #pragma unroll
    for (int i = 0; i < 4; ++i) {
      int e = w*16 + i*4 + (lane >> 4);
      int kb = (lane & 15) ^ (e & 7);
      gld16(wp + (size_t)e*DH + kb*8, &Wsh[w*16 + i*4][0]);
    }
    __syncthreads();
    f32x4 yacc[8];
    #pragma unroll
    for (int i = 0; i < 8; ++i) yacc[i] = (f32x4){0.f,0.f,0.f,0.f};
    #pragma unroll
    for (int sub = 0; sub < 8; ++sub) {
      int e = 16*sub + lr;
      #pragma unroll
      for (int ks = 0; ks < 4; ++ks) {
        int ch = (lg + 4*ks) ^ (lr & 7);
        bf16x8 bhv = *(const bf16x8*)&Wsh[e][ch*8];
        yacc[sub] = __builtin_amdgcn_mfma_f32_16x16x32_bf16(xh[ks], bhv, yacc[sub], 0, 0, 0);
      }
    }
    if (which < 2) {
      const float* st = tabs + (which ? 2*SEQ*HALF : 0);
      const float* ct = st + SEQ*HALF;
      bf16_t* Op = which ? Ko : Qo;
      #pragma unroll
      for (int sub = 0; sub < 8; ++sub) {
        int e = 16*sub + lr;
        int i = e >> 1;
        #pragma unroll
        for (int reg = 0; reg < 4; ++reg) {
          float v = yacc[sub][reg];
          float p = __shfl_xor(v, 1);
          int tau = 16*w + 4*lg + reg;
          int srow = s0 + tau;
          float sv = st[srow*HALF + i], cv = ct[srow*HALF + i];
          float o = v * cv + ((e & 1) ? p : -p) * sv;
          bf16_t ob = (bf16_t)o;
          Op[(bh*SEQ + srow) * DH + e] = ob;
          if (which == 1) {             // stash K^T for delta
            int col = (((tau>>3) ^ (e & 7)) << 3) | (tau & 7);
            KT[e][col] = ob;
          }
        }
      }
    } else {
      float decay[4];
      #pragma unroll
      for (int reg = 0; reg < 4; ++reg)
        decay[reg] = exp2f(l2g * (float)(127 - (16*w + 4*lg + reg)));
      #pragma unroll
      for (int sub = 0; sub < 8; ++sub) {
        int e = 16*sub + lr;
        bf16x4 hv;
        #pragma unroll
        for (int reg = 0; reg < 4; ++reg) {
          int tau = 16*w + 4*lg + reg;
          float f = yacc[sub][reg];
          hv[reg] = (bf16_t)f;
          int col = (((tau>>3) ^ (e & 7)) << 3) | (tau & 7);
          Vd[e][col] = (bf16_t)(f * decay[reg]);
        }
        *(bf16x4*)(VTo + bh * (size_t)(DH*SEQ) + (size_t)e*SEQ + (s0 + 16*w + 4*lg)) = hv;
      }
    }
  }
  __syncthreads();                      // KT / Vd complete

  // ---- delta: Dt[dv][dk] = sum_tau Vd[dv][tau] * KT[dk][tau] ----
  f32x4 acc[8];
  #pragma unroll
  for (int s = 0; s < 8; ++s) acc[s] = (f32x4){0.f,0.f,0.f,0.f};
  {
    int dv = 16*w + lr;
    #pragma unroll
    for (int ks = 0; ks < 4; ++ks) {
      int ca = (lg + 4*ks) ^ (dv & 7);
      bf16x8 avh = *(const bf16x8*)&Vd[dv][ca*8];
      #pragma unroll
      for (int sub = 0; sub < 8; ++sub) {
        int dk = 16*sub + lr;
        int cb = (lg + 4*ks) ^ (dk & 7);
        bf16x8 bkh = *(const bf16x8*)&KT[dk][cb*8];
        acc[sub] = __builtin_amdgcn_mfma_f32_16x16x32_bf16(avh, bkh, acc[sub], 0, 0, 0);
      }
    }
  }
  size_t obase = (bh * 16 + c) * 16384;
  #pragma unroll
  for (int sub = 0; sub < 8; ++sub)
    #pragma unroll
    for (int reg = 0; reg < 4; ++reg) {
      int dv = 16*w + 4*lg + reg;
      int dk = 16*sub + lr;
      DSt[obase + (size_t)dv*128 + dk] = (bf16_t)acc[sub][reg];
    }
}

// ---------------- retention: in-block scan + cross + intra + groupnorm -----
// flat grid: blocks 0..255 = retention (c=bid&15, bh=bid>>4);
// blocks 256..767 = Wg/Wo transposes (hidden under ret). 512 thr.
__global__ __launch_bounds__(512, 1) void k_ret(
    const bf16_t* __restrict__ Qg, const bf16_t* __restrict__ Kg,
    const bf16_t* __restrict__ VTg, const bf16_t* __restrict__ DSt,
    const float* __restrict__ gw, const float* __restrict__ gb,
    bf16_t* __restrict__ Yn,
    const float* __restrict__ Wg, const float* __restrict__ Wo,
    bf16_t* __restrict__ Wgt, bf16_t* __restrict__ Wot) {
  __shared__ bf16_t Ksh[64][128];
  __shared__ bf16_t Vsh[128][64];
  __shared__ bf16_t Ph[128][64];
  __shared__ bf16_t Slds[128][128];
  __shared__ float tile[64][65];
  int t = threadIdx.x;
  int bid = blockIdx.x;
  if (bid >= 256) {
    int i = bid - 256;               // 512 blocks: 2 x (16x16)
    int which = i >> 8;
    int j = i & 255;
    wsplit_body(which ? Wo : Wg, which ? Wot : Wgt, HD, HD,
                j & 15, j >> 4, 0, tile, 512, t);
    return;
  }
  int lane = t & 63, w = t >> 6;          // 8 waves
  int lr = lane & 15, lg = lane >> 4;
  int c = bid & 15, bh = bid >> 4, hh = bh & 7;
  int s0 = c * 128;
  size_t base  = (size_t)bh * SEQ * DH;
  size_t vbase = (size_t)bh * DH * SEQ;
  float l2g = head_l2g(hh);
  float colf = exp2f(-l2g * (float)lr);
  float g16v[4];
  #pragma unroll
  for (int ts = 0; ts < 4; ++ts) g16v[ts] = exp2f(-l2g * (float)(16*ts));

  // ---- issue async staging of intra tile 0 (K rows, V cols s0..s0+63) ----
  #pragma unroll
  for (int i = 0; i < 2; ++i) {
    int r = w*8 + i*4 + (lane >> 4);
    int kb = (lane & 15) ^ (r & 7);
    gld16(Kg + base + (size_t)(s0 + r)*DH + kb*8, &Ksh[w*8 + i*4][0]);
  }
  #pragma unroll
  for (int i = 0; i < 2; ++i) {
    int d = w*16 + i*8 + (lane >> 3);
    int cb = (lane & 7) ^ (d & 7);
    gld16(VTg + vbase + (size_t)d*SEQ + s0 + cb*8, &Vsh[w*16 + i*8][0]);
  }

  // ---- Q fragments ----
  bf16x8 qh[4];
  {
    const bf16_t* qp = Qg + base + (size_t)(s0 + 16*w + lr) * DH + lg * 8;
    #pragma unroll
    for (int ks = 0; ks < 4; ++ks)
      qh[ks] = *(const bf16x8*)(qp + 32*ks);
  }

  // ---- in-block scan: S_c = sum_{cp<c} g128^(c-1-cp) * Δ_cp  (fp32) ----
  {
    float g128 = exp2f(l2g * 128.0f);
    float S0[8] = {}, S1[8] = {}, S2[8] = {}, S3[8] = {};
    const bf16_t* dbase = DSt + ((size_t)bh * 16) * 16384
                        + (size_t)(t >> 2) * 128 + (t & 3) * 32;
    for (int cp = 0; cp < c; ++cp) {
      const bf16_t* dp = dbase + (size_t)cp * 16384;
      bf16x8 d0 = *(const bf16x8*)dp;
      bf16x8 d1 = *(const bf16x8*)(dp + 8);
      bf16x8 d2 = *(const bf16x8*)(dp + 16);
      bf16x8 d3 = *(const bf16x8*)(dp + 24);
      #pragma unroll
      for (int j = 0; j < 8; ++j) {
        S0[j] = g128*S0[j] + (float)d0[j];
        S1[j] = g128*S1[j] + (float)d1[j];
        S2[j] = g128*S2[j] + (float)d2[j];
        S3[j] = g128*S3[j] + (float)d3[j];
      }
    }
    int dv = t >> 2;
    #pragma unroll
    for (int q4 = 0; q4 < 4; ++q4) {
      const float* Sq = (q4 == 0) ? S0 : (q4 == 1) ? S1 : (q4 == 2) ? S2 : S3;
      int ch = ((t & 3) * 4 + q4) ^ (dv & 7);
      bf16x8 s8;
      #pragma unroll
      for (int j = 0; j < 8; ++j) s8[j] = (bf16_t)Sq[j];
      *(bf16x8*)&Slds[dv][ch*8] = s8;
    }
  }
  __syncthreads();   // tile0 gld16 + Slds writes complete

  // ---- cross: yacc = Q · S^T (B-frags from LDS) ----
  f32x4 yacc[8];
  #pragma unroll
  for (int i = 0; i < 8; ++i) yacc[i] = (f32x4){0.f,0.f,0.f,0.f};
  {
    #pragma unroll
    for (int sub = 0; sub < 8; ++sub) {
      int dv = 16*sub + lr;
      #pragma unroll
      for (int ks = 0; ks < 4; ++ks) {
        int ch = (lg + 4*ks) ^ (dv & 7);
        bf16x8 b8 = *(const bf16x8*)&Slds[dv][ch*8];
        yacc[sub] = __builtin_amdgcn_mfma_f32_16x16x32_bf16(qh[ks], b8, yacc[sub], 0, 0, 0);
      }
    }
    float rowc[4];
    #pragma unroll
    for (int reg = 0; reg < 4; ++reg)
      rowc[reg] = exp2f(l2g * (float)(16*w + 4*lg + reg + 1));
    #pragma unroll
    for (int sub = 0; sub < 8; ++sub)
      #pragma unroll
      for (int reg = 0; reg < 4; ++reg)
        yacc[sub][reg] *= rowc[reg];
  }

  // ---- intra tiles ----
  for (int kt = 0; kt < 2; ++kt) {
    int t0 = kt * 64;
    if (kt == 1) {
      __syncthreads();   // all waves done reading tile 0
      #pragma unroll
      for (int i = 0; i < 2; ++i) {
        int r = w*8 + i*4 + (lane >> 4);
        int kb = (lane & 15) ^ (r & 7);
        gld16(Kg + base + (size_t)(s0 + 64 + r)*DH + kb*8, &Ksh[w*8 + i*4][0]);
      }
      #pragma unroll
      for (int i = 0; i < 2; ++i) {
        int d = w*16 + i*8 + (lane >> 3);
        int cb = (lane & 7) ^ (d & 7);
        gld16(VTg + vbase + (size_t)d*SEQ + s0 + 64 + cb*8, &Vsh[w*16 + i*8][0]);
      }
      __syncthreads();   // tile 1 staged
    }
    if (!(kt == 1 && w < 4)) {
      float rowf[4];
      #pragma unroll
      for (int reg = 0; reg < 4; ++reg)
        rowf[reg] = exp2f(l2g * (float)(16*w + 4*lg + reg - t0));

      #pragma unroll
      for (int ts = 0; ts < 4; ++ts) {
        f32x4 sacc = (f32x4){0.f,0.f,0.f,0.f};
        int trow = 16*ts + lr;
        #pragma unroll
        for (int ks = 0; ks < 4; ++ks) {
          int kbs = (4*ks + lg) ^ (trow & 7);
          bf16x8 kh8 = *(const bf16x8*)&Ksh[trow][kbs*8];
          sacc = __builtin_amdgcn_mfma_f32_16x16x32_bf16(qh[ks], kh8, sacc, 0, 0, 0);
        }
        float cf = colf * g16v[ts];
        #pragma unroll
        for (int reg = 0; reg < 4; ++reg) {
          int qloc = 4*lg + reg;
          int diff = (16*w + qloc) - (t0 + trow);
          float p = (diff >= 0) ? sacc[reg] * (rowf[reg] * cf) : 0.0f;
          int cb = (trow >> 3) ^ (qloc & 7);
          Ph[16*w + qloc][cb*8 + (trow & 7)] = (bf16_t)p;
        }
      }
      #pragma unroll
      for (int ks = 0; ks < 2; ++ks) {
        int prow = 16*w + lr;
        int pcb = (4*ks + lg) ^ (lr & 7);
        bf16x8 pah = *(const bf16x8*)&Ph[prow][pcb*8];
        #pragma unroll
        for (int sub = 0; sub < 8; ++sub) {
          int drow = 16*sub + lr;
          int vcb = (4*ks + lg) ^ (drow & 7);
          bf16x8 vh8 = *(const bf16x8*)&Vsh[drow][vcb*8];
          yacc[sub] = __builtin_amdgcn_mfma_f32_16x16x32_bf16(pah, vh8, yacc[sub], 0, 0, 0);
        }
      }
    }
  }

  // ---- fused groupnorm (bf16 out) ----
  float s1v[4] = {0.f,0.f,0.f,0.f}, s2v[4] = {0.f,0.f,0.f,0.f};
  #pragma unroll
  for (int sub = 0; sub < 8; ++sub)
    #pragma unroll
    for (int reg = 0; reg < 4; ++reg) {
      float v = yacc[sub][reg];
      s1v[reg] += v;
      s2v[reg] += v * v;
    }
  #pragma unroll
  for (int off = 8; off; off >>= 1)
    #pragma unroll
    for (int reg = 0; reg < 4; ++reg) {
      s1v[reg] += __shfl_xor(s1v[reg], off);
      s2v[reg] += __shfl_xor(s2v[reg], off);
    }
  float gwv[8], gbv[8];
  #pragma unroll
  for (int sub = 0; sub < 8; ++sub) {
    gwv[sub] = gw[hh*DH + 16*sub + lr];
    gbv[sub] = gb[hh*DH + 16*sub + lr];
  }
  int b = bh >> 3;
  #pragma unroll
  for (int reg = 0; reg < 4; ++reg) {
    float mean = s1v[reg] * (1.0f/128.0f);
    float var = s2v[reg] * (1.0f/128.0f) - mean*mean;
    float inv = rsqrtf(var + 1e-5f);
    int srow = s0 + 16*w + 4*lg + reg;
    bf16_t* op = Yn + (size_t)(b*SEQ + srow) * HD + hh*DH;
    #pragma unroll
    for (int sub = 0; sub < 8; ++sub)
      op[16*sub + lr] = (bf16_t)((yacc[sub][reg] - mean) * inv * gwv[sub] + gbv[sub]);
  }
}

// ---------------- plain-bf16 MFMA GEMM, 64x128 tile, 2 blocks/CU -----------
__global__ __launch_bounds__(256, 2) void k_gemm(
    const bf16_t* __restrict__ Ag, const bf16_t* __restrict__ Bg,
    const bf16_t* __restrict__ E,
    bf16_t* __restrict__ Oh, float* __restrict__ Of, int mode) {
  __shared__ bf16_t SA[2][64][64];
  __shared__ bf16_t SBB[2][128][64];
  int t = threadIdx.x;
  int lane = t & 63, w = t >> 6;          // 4 waves
  int lr = lane & 15, lg = lane >> 4;
  int wr = w >> 1, wc = w & 1;            // wave tile: 32(m) x 64(n)
  int bid = blockIdx.x;                   // 512 blocks
  int xcd = bid & 7, local = bid >> 3;
  int mp = xcd * 8 + (local >> 3);        // 64 m-panels, 8 contiguous per XCD
  int np = local & 7;                     // 8 n-panels
  int m0 = mp * 64, n0 = np * 128;

  const bf16_t* As = Ag + (size_t)m0 * HD;
  const bf16_t* Bs = Bg + (size_t)n0 * HD;

  f32x4 acc[2][4];
  #pragma unroll
  for (int i = 0; i < 2; ++i)
    #pragma unroll
    for (int j = 0; j < 4; ++j) acc[i][j] = (f32x4){0.f,0.f,0.f,0.f};

  int srow = lane >> 3, sch = lane & 7;

  {
    #pragma unroll
    for (int i = 0; i < 2; ++i) {
      int row = w*16 + i*8 + srow;
      int kc = (sch ^ (row & 7)) * 8;
      gld16(As + (size_t)row*HD + kc, &SA[0][w*16 + i*8][0]);
    }
    #pragma unroll
    for (int i = 0; i < 4; ++i) {
      int row = w*32 + i*8 + srow;
      int kc = (sch ^ (row & 7)) * 8;
      gld16(Bs + (size_t)row*HD + kc, &SBB[0][w*32 + i*8][0]);
    }
  }
  __syncthreads();

  int buf = 0;
  for (int kt = 0; kt < 16; ++kt) {
    if (kt + 1 < 16) {
      int k0 = (kt + 1) * 64;
      #pragma unroll
      for (int i = 0; i < 2; ++i) {
        int row = w*16 + i*8 + srow;
        int kc = (sch ^ (row & 7)) * 8;
        gld16(As + (size_t)row*HD + k0 + kc, &SA[buf^1][w*16 + i*8][0]);
      }
      #pragma unroll
      for (int i = 0; i < 4; ++i) {
        int row = w*32 + i*8 + srow;
        int kc = (sch ^ (row & 7)) * 8;
        gld16(Bs + (size_t)row*HD + k0 + kc, &SBB[buf^1][w*32 + i*8][0]);
      }
    }
    #pragma unroll
    for (int ks = 0; ks < 2; ++ks) {
      bf16x8 a_[2], b_[4];
      #pragma unroll
      for (int mf = 0; mf < 2; ++mf) {
        int row = wr*32 + mf*16 + lr;
        int ch = (lg + 4*ks) ^ (row & 7);
        a_[mf] = *(const bf16x8*)&SA[buf][row][ch*8];
      }
      #pragma unroll
      for (int nf = 0; nf < 4; ++nf) {
        int row = wc*64 + nf*16 + lr;
        int ch = (lg + 4*ks) ^ (row & 7);
        b_[nf] = *(const bf16x8*)&SBB[buf][row][ch*8];
      }
      #pragma unroll
      for (int mf = 0; mf < 2; ++mf)
        #pragma unroll
        for (int nf = 0; nf < 4; ++nf)
          acc[mf][nf] = __builtin_amdgcn_mfma_f32_16x16x32_bf16(a_[mf], b_[nf], acc[mf][nf], 0, 0, 0);
    }
    __syncthreads();
    buf ^= 1;
  }
  #pragma unroll
  for (int mf = 0; mf < 2; ++mf) {
    #pragma unroll
    for (int nf = 0; nf < 4; ++nf) {
      #pragma unroll
      for (int reg = 0; reg < 4; ++reg) {
        int m = m0 + wr*32 + mf*16 + 4*lg + reg;
        int n = n0 + wc*64 + nf*16 + lr;
        float g = acc[mf][nf][reg];
        size_t off = (size_t)m * HD + n;
        if (mode == 1) {
          float sg = 1.0f / (1.0f + expf(-g));
          Oh[off] = (bf16_t)(g * sg * (float)E[off]);
        } else {
          Of[off] = g;
        }
      }
    }
  }
}

extern "C" void kernel_launch(void* const* d_in, const int* in_sizes, int n_in,
                              void* d_out, int out_size, void* d_ws, size_t ws_size,
                              hipStream_t stream) {
  const float* X  = (const float*)d_in[0];
  const float* Wq = (const float*)d_in[1];
  const float* Wk = (const float*)d_in[2];
  const float* Wv = (const float*)d_in[3];
  const float* Wg = (const float*)d_in[4];
  const float* Wo = (const float*)d_in[5];
  const float* gw = (const float*)d_in[6];
  const float* gb = (const float*)d_in[7];
  float* out = (float*)d_out;
  float* ws = (float*)d_ws;

  // ws: tabs 2.1MB | Q K VT 3x8.4 | Yn 8.4 | DSt 8.4 | W ~4.8 | Xh 8.4 (~57MB)
  float* tabs = ws;
  bf16_t* Q   = (bf16_t*)(ws + 524288);
  bf16_t* K   = Q + 4194304;
  bf16_t* VT  = K + 4194304;
  bf16_t* Yn  = VT + 4194304;
  bf16_t* DSt = Yn + 4194304;
  bf16_t* Wqt = DSt + 4194304;
  bf16_t* Wkt = Wqt + 131072;
  bf16_t* Wvt = Wkt + 131072;
  bf16_t* Wgt = Wvt + 131072;
  bf16_t* Wot = Wgt + 1048576;
  bf16_t* Xh  = Wot + 1048576;
  bf16_t* A2  = Q;                 // Q dead after k_ret

  k_prep<<<dim3(608), dim3(256), 0, stream>>>(Wq, Wk, Wv, tabs, Wqt, Wkt, Wvt);
  k_qkvd<<<dim3(16, 8, 2), dim3(512), 0, stream>>>(X, tabs, Wqt, Wkt, Wvt,
                                                   Q, K, VT, Xh, DSt);
  k_ret<<<dim3(768), dim3(512), 0, stream>>>(Q, K, VT, DSt, gw, gb, Yn,
                                             Wg, Wo, Wgt, Wot);
  k_gemm<<<dim3(512), dim3(256), 0, stream>>>(Xh, Wgt, Yn, A2, nullptr, 1);
  k_gemm<<<dim3(512), dim3(256), 0, stream>>>(A2, Wot, nullptr, nullptr, out, 0);
}

// Round 14
// 94.827 us; speedup vs baseline: 2.4288x; 1.0050x over previous
//
#include <hip/hip_runtime.h>
#include <math.h>

#define NB 2
#define SEQ 2048
#define HD 1024
#define NH 8
#define DH 128
#define HALF 64

typedef __bf16 bf16_t;
typedef __attribute__((ext_vector_type(8))) __bf16 bf16x8;
typedef __attribute__((ext_vector_type(4))) __bf16 bf16x4;
typedef __attribute__((ext_vector_type(4))) float f32x4;

typedef __attribute__((address_space(1))) void gvoid;
typedef __attribute__((address_space(3))) void lvoid;

__device__ __forceinline__ void gld16(const bf16_t* g, bf16_t* l) {
  __builtin_amdgcn_global_load_lds((gvoid*)g, (lvoid*)l, 16, 0, 0);
}

__device__ __forceinline__ float head_l2g(int hh) {
  double ga = log(1.0/32.0), gbb = log(1.0/512.0);
  float gamma = (float)(1.0 - exp(ga + (double)hh * (gbb - ga) / 7.0));
  return log2f(gamma);
}

// shared transpose+cast body (stride-parameterized)
__device__ __forceinline__ void wsplit_body(
    const float* in, bf16_t* oh, int M, int N,
    int bx, int by, int z, float (*tile)[65], int nthr, int t) {
  in += (size_t)z * M * N; oh += (size_t)z * M * N;
  int r0 = by * 64, c0 = bx * 64;
  for (int idx = t; idx < 1024; idx += nthr) {
    int r = idx >> 4, c4 = (idx & 15) * 4;
    float4 v = *(const float4*)(in + (size_t)(r0 + r) * N + c0 + c4);
    *(float4*)&tile[r][c4] = v;
  }
  __syncthreads();
  for (int idx = t; idx < 1024; idx += nthr) {
    int c = idx >> 4, r4 = (idx & 15) * 4;
    bf16x4 h;
    #pragma unroll
    for (int j = 0; j < 4; ++j)
      h[j] = (bf16_t)tile[r4 + j][c];
    *(bf16x4*)(oh + (size_t)(c0 + c) * M + r0 + r4) = h;
  }
}

// ---------------- prep: xpos tables + QKV weight transposes ----------------
__global__ __launch_bounds__(256) void k_prep(
    const float* __restrict__ Wq, const float* __restrict__ Wk,
    const float* __restrict__ Wv,
    float* __restrict__ tabs, bf16_t* __restrict__ Wqt,
    bf16_t* __restrict__ Wkt, bf16_t* __restrict__ Wvt) {
  __shared__ float tile[64][65];
  int b = blockIdx.x;
  if (b < 512) {
    int idx = b * 256 + threadIdx.x;
    int s = idx >> 6, i = idx & 63;
    float dd = (float)DH;
    float scale = (2.0f * (float)i + 0.4f * dd) / (1.4f * dd);
    float sc = expf(logf(scale) * ((float)s / 512.0f));
    float inv_freq = expf(-logf(10000.0f) * ((float)i / (float)HALF));
    float ang = (float)s * inv_freq;
    float sn, cs;
    sincosf(ang, &sn, &cs);
    float rsc = 1.0f / sc;
    tabs[idx]               = sn * sc;
    tabs[SEQ*HALF + idx]    = cs * sc;
    tabs[2*SEQ*HALF + idx]  = sn * rsc;
    tabs[3*SEQ*HALF + idx]  = cs * rsc;
  } else {
    int i = b - 512;               // 96 blocks: 3 x (2x2x8)
    int which = i >> 5;
    int j = i & 31;
    const float* in = (which == 0) ? Wq : (which == 1) ? Wk : Wv;
    bf16_t* oh = (which == 0) ? Wqt : (which == 1) ? Wkt : Wvt;
    wsplit_body(in, oh, DH, DH, j & 1, (j >> 1) & 1, j >> 2, tile,
                256, threadIdx.x);
  }
}

// ---------------- fused QKV projection + xpos + per-chunk delta ------------
// grid (16 chunks, 8 heads, 2 batch), 512 thr, 96KB LDS.
// VT now written via LDS round-trip (Wsh reuse) -> coalesced 64B segments.
__global__ __launch_bounds__(512, 1) void k_qkvd(
    const float* __restrict__ X, const float* __restrict__ tabs,
    const bf16_t* __restrict__ Wqt, const bf16_t* __restrict__ Wkt,
    const bf16_t* __restrict__ Wvt,
    bf16_t* __restrict__ Qo, bf16_t* __restrict__ Ko,
    bf16_t* __restrict__ VTo, bf16_t* __restrict__ Xhg,
    bf16_t* __restrict__ DSt) {
  __shared__ bf16_t Wsh[128][128];     // W^T tile; reused as undecayed V^T
  __shared__ bf16_t KT[128][128];      // [dk][tau], chunk-swz (post-xpos K)
  __shared__ bf16_t Vd[128][128];      // [dv][tau], chunk-swz (decayed V)
  int t = threadIdx.x;
  int lane = t & 63, w = t >> 6;       // 8 waves
  int lr = lane & 15, lg = lane >> 4;
  int c = blockIdx.x, hh = blockIdx.y, b = blockIdx.z;
  int s0 = c * 128;
  size_t bh = (size_t)(b*NH + hh);
  float l2g = head_l2g(hh);

  bf16x8 xh[4];
  {
    const float* xp = X + ((size_t)(b*SEQ + s0 + 16*w + lr)) * HD + hh*DH + 8*lg;
    #pragma unroll
    for (int ks = 0; ks < 4; ++ks) {
      float4 u = *(const float4*)(xp + 32*ks);
      float4 v = *(const float4*)(xp + 32*ks + 4);
      float fv[8] = {u.x,u.y,u.z,u.w,v.x,v.y,v.z,v.w};
      #pragma unroll
      for (int j = 0; j < 8; ++j) xh[ks][j] = (bf16_t)fv[j];
    }
  }
  {
    bf16_t* xo = Xhg + ((size_t)(b*SEQ + s0 + 16*w + lr)) * HD + hh*DH + 8*lg;
    #pragma unroll
    for (int ks = 0; ks < 4; ++ks)
      *(bf16x8*)(xo + 32*ks) = xh[ks];
  }

  const bf16_t* Wp[3] = {Wqt, Wkt, Wvt};

  for (int which = 0; which < 3; ++which) {
    const bf16_t* wp = Wp[which] + (size_t)hh * (DH*DH);
    __syncthreads();                    // Wsh free (prev pass done)
    // async stage W^T: wave w rows [w*16, w*16+16), pre-swizzled source
    #pragma unroll
    for (int i = 0; i < 4; ++i) {
      int e = w*16 + i*4 + (lane >> 4);
      int kb = (lane & 15) ^ (e & 7);
      gld16(wp + (size_t)e*DH + kb*8, &Wsh[w*16 + i*4][0]);
    }
    __syncthreads();
    f32x4 yacc[8];
    #pragma unroll
    for (int i = 0; i < 8; ++i) yacc[i] = (f32x4){0.f,0.f,0.f,0.f};
    #pragma unroll
    for (int sub = 0; sub < 8; ++sub) {
      int e = 16*sub + lr;
      #pragma unroll
      for (int ks = 0; ks < 4; ++ks) {
        int ch = (lg + 4*ks) ^ (lr & 7);
        bf16x8 bhv = *(const bf16x8*)&Wsh[e][ch*8];
        yacc[sub] = __builtin_amdgcn_mfma_f32_16x16x32_bf16(xh[ks], bhv, yacc[sub], 0, 0, 0);
      }
    }
    if (which < 2) {
      const float* st = tabs + (which ? 2*SEQ*HALF : 0);
      const float* ct = st + SEQ*HALF;
      bf16_t* Op = which ? Ko : Qo;
      #pragma unroll
      for (int sub = 0; sub < 8; ++sub) {
        int e = 16*sub + lr;
        int i = e >> 1;
        #pragma unroll
        for (int reg = 0; reg < 4; ++reg) {
          float v = yacc[sub][reg];
          float p = __shfl_xor(v, 1);
          int tau = 16*w + 4*lg + reg;
          int srow = s0 + tau;
          float sv = st[srow*HALF + i], cv = ct[srow*HALF + i];
          float o = v * cv + ((e & 1) ? p : -p) * sv;
          bf16_t ob = (bf16_t)o;
          Op[(bh*SEQ + srow) * DH + e] = ob;
          if (which == 1) {             // stash K^T for delta
            int col = (((tau>>3) ^ (e & 7)) << 3) | (tau & 7);
            KT[e][col] = ob;
          }
        }
      }
    } else {
      float decay[4];
      #pragma unroll
      for (int reg = 0; reg < 4; ++reg)
        decay[reg] = exp2f(l2g * (float)(127 - (16*w + 4*lg + reg)));
      // decayed V^T for delta (as before)
      #pragma unroll
      for (int sub = 0; sub < 8; ++sub) {
        int e = 16*sub + lr;
        #pragma unroll
        for (int reg = 0; reg < 4; ++reg) {
          int tau = 16*w + 4*lg + reg;
          float f = yacc[sub][reg];
          int col = (((tau>>3) ^ (e & 7)) << 3) | (tau & 7);
          Vd[e][col] = (bf16_t)(f * decay[reg]);
        }
      }
      __syncthreads();                  // all MFMA reads of Wsh done
      // undecayed V^T into Wsh (same swizzled scatter pattern)
      #pragma unroll
      for (int sub = 0; sub < 8; ++sub) {
        int e = 16*sub + lr;
        #pragma unroll
        for (int reg = 0; reg < 4; ++reg) {
          int tau = 16*w + 4*lg + reg;
          int col = (((tau>>3) ^ (e & 7)) << 3) | (tau & 7);
          Wsh[e][col] = (bf16_t)yacc[sub][reg];
        }
      }
      __syncthreads();
      // coalesced VT global write: 4 threads/row, 64B contiguous per 4 lanes
      {
        int e = t >> 2, q = t & 3;
        bf16_t* vo = VTo + bh * (size_t)(DH*SEQ) + (size_t)e*SEQ + s0;
        #pragma unroll
        for (int j = 0; j < 4; ++j) {
          int tau0 = j*32 + q*8;
          int col = (((tau0 >> 3) ^ (e & 7)) << 3);
          *(bf16x8*)(vo + tau0) = *(const bf16x8*)&Wsh[e][col];
        }
      }
    }
  }
  __syncthreads();                      // KT / Vd complete

  // ---- delta: Dt[dv][dk] = sum_tau Vd[dv][tau] * KT[dk][tau] ----
  f32x4 acc[8];
  #pragma unroll
  for (int s = 0; s < 8; ++s) acc[s] = (f32x4){0.f,0.f,0.f,0.f};
  {
    int dv = 16*w + lr;
    #pragma unroll
    for (int ks = 0; ks < 4; ++ks) {
      int ca = (lg + 4*ks) ^ (dv & 7);
      bf16x8 avh = *(const bf16x8*)&Vd[dv][ca*8];
      #pragma unroll
      for (int sub = 0; sub < 8; ++sub) {
        int dk = 16*sub + lr;
        int cb = (lg + 4*ks) ^ (dk & 7);
        bf16x8 bkh = *(const bf16x8*)&KT[dk][cb*8];
        acc[sub] = __builtin_amdgcn_mfma_f32_16x16x32_bf16(avh, bkh, acc[sub], 0, 0, 0);
      }
    }
  }
  size_t obase = (bh * 16 + c) * 16384;
  #pragma unroll
  for (int sub = 0; sub < 8; ++sub)
    #pragma unroll
    for (int reg = 0; reg < 4; ++reg) {
      int dv = 16*w + 4*lg + reg;
      int dk = 16*sub + lr;
      DSt[obase + (size_t)dv*128 + dk] = (bf16_t)acc[sub][reg];
    }
}

// ---------------- retention: in-block scan + cross + intra + groupnorm -----
// flat grid: blocks 0..255 = retention (c=bid&15, bh=bid>>4);
// blocks 256..767 = Wg/Wo transposes (hidden under ret). 512 thr.
__global__ __launch_bounds__(512, 1) void k_ret(
    const bf16_t* __restrict__ Qg, const bf16_t* __restrict__ Kg,
    const bf16_t* __restrict__ VTg, const bf16_t* __restrict__ DSt,
    const float* __restrict__ gw, const float* __restrict__ gb,
    bf16_t* __restrict__ Yn,
    const float* __restrict__ Wg, const float* __restrict__ Wo,
    bf16_t* __restrict__ Wgt, bf16_t* __restrict__ Wot) {
  __shared__ bf16_t Ksh[64][128];
  __shared__ bf16_t Vsh[128][64];
  __shared__ bf16_t Ph[128][64];
  __shared__ bf16_t Slds[128][128];
  __shared__ float tile[64][65];
  int t = threadIdx.x;
  int bid = blockIdx.x;
  if (bid >= 256) {
    int i = bid - 256;               // 512 blocks: 2 x (16x16)
    int which = i >> 8;
    int j = i & 255;
    wsplit_body(which ? Wo : Wg, which ? Wot : Wgt, HD, HD,
                j & 15, j >> 4, 0, tile, 512, t);
    return;
  }
  int lane = t & 63, w = t >> 6;          // 8 waves
  int lr = lane & 15, lg = lane >> 4;
  int c = bid & 15, bh = bid >> 4, hh = bh & 7;
  int s0 = c * 128;
  size_t base  = (size_t)bh * SEQ * DH;
  size_t vbase = (size_t)bh * DH * SEQ;
  float l2g = head_l2g(hh);
  float colf = exp2f(-l2g * (float)lr);
  float g16v[4];
  #pragma unroll
  for (int ts = 0; ts < 4; ++ts) g16v[ts] = exp2f(-l2g * (float)(16*ts));

  // ---- issue async staging of intra tile 0 (K rows, V cols s0..s0+63) ----
  #pragma unroll
  for (int i = 0; i < 2; ++i) {
    int r = w*8 + i*4 + (lane >> 4);
    int kb = (lane & 15) ^ (r & 7);
    gld16(Kg + base + (size_t)(s0 + r)*DH + kb*8, &Ksh[w*8 + i*4][0]);
  }
  #pragma unroll
  for (int i = 0; i < 2; ++i) {
    int d = w*16 + i*8 + (lane >> 3);
    int cb = (lane & 7) ^ (d & 7);
    gld16(VTg + vbase + (size_t)d*SEQ + s0 + cb*8, &Vsh[w*16 + i*8][0]);
  }

  // ---- Q fragments ----
  bf16x8 qh[4];
  {
    const bf16_t* qp = Qg + base + (size_t)(s0 + 16*w + lr) * DH + lg * 8;
    #pragma unroll
    for (int ks = 0; ks < 4; ++ks)
      qh[ks] = *(const bf16x8*)(qp + 32*ks);
  }

  // ---- in-block scan: S_c = sum_{cp<c} g128^(c-1-cp) * Δ_cp  (fp32) ----
  {
    float g128 = exp2f(l2g * 128.0f);
    float S0[8] = {}, S1[8] = {}, S2[8] = {}, S3[8] = {};
    const bf16_t* dbase = DSt + ((size_t)bh * 16) * 16384
                        + (size_t)(t >> 2) * 128 + (t & 3) * 32;
    for (int cp = 0; cp < c; ++cp) {
      const bf16_t* dp = dbase + (size_t)cp * 16384;
      bf16x8 d0 = *(const bf16x8*)dp;
      bf16x8 d1 = *(const bf16x8*)(dp + 8);
      bf16x8 d2 = *(const bf16x8*)(dp + 16);
      bf16x8 d3 = *(const bf16x8*)(dp + 24);
      #pragma unroll
      for (int j = 0; j < 8; ++j) {
        S0[j] = g128*S0[j] + (float)d0[j];
        S1[j] = g128*S1[j] + (float)d1[j];
        S2[j] = g128*S2[j] + (float)d2[j];
        S3[j] = g128*S3[j] + (float)d3[j];
      }
    }
    int dv = t >> 2;
    #pragma unroll
    for (int q4 = 0; q4 < 4; ++q4) {
      const float* Sq = (q4 == 0) ? S0 : (q4 == 1) ? S1 : (q4 == 2) ? S2 : S3;
      int ch = ((t & 3) * 4 + q4) ^ (dv & 7);
      bf16x8 s8;
      #pragma unroll
      for (int j = 0; j < 8; ++j) s8[j] = (bf16_t)Sq[j];
      *(bf16x8*)&Slds[dv][ch*8] = s8;
    }
  }
  __syncthreads();   // tile0 gld16 + Slds writes complete

  // ---- cross: yacc = Q · S^T (B-frags from LDS) ----
  f32x4 yacc[8];
  #pragma unroll
  for (int i = 0; i < 8; ++i) yacc[i] = (f32x4){0.f,0.f,0.f,0.f};
  {
    #pragma unroll
    for (int sub = 0; sub < 8; ++sub) {
      int dv = 16*sub + lr;
      #pragma unroll
      for (int ks = 0; ks < 4; ++ks) {
        int ch = (lg + 4*ks) ^ (dv & 7);
        bf16x8 b8 = *(const bf16x8*)&Slds[dv][ch*8];
        yacc[sub] = __builtin_amdgcn_mfma_f32_16x16x32_bf16(qh[ks], b8, yacc[sub], 0, 0, 0);
      }
    }
    float rowc[4];
    #pragma unroll
    for (int reg = 0; reg < 4; ++reg)
      rowc[reg] = exp2f(l2g * (float)(16*w + 4*lg + reg + 1));
    #pragma unroll
    for (int sub = 0; sub < 8; ++sub)
      #pragma unroll
      for (int reg = 0; reg < 4; ++reg)
        yacc[sub][reg] *= rowc[reg];
  }

  // ---- intra tiles ----
  for (int kt = 0; kt < 2; ++kt) {
    int t0 = kt * 64;
    if (kt == 1) {
      __syncthreads();   // all waves done reading tile 0
      #pragma unroll
      for (int i = 0; i < 2; ++i) {
        int r = w*8 + i*4 + (lane >> 4);
        int kb = (lane & 15) ^ (r & 7);
        gld16(Kg + base + (size_t)(s0 + 64 + r)*DH + kb*8, &Ksh[w*8 + i*4][0]);
      }
      #pragma unroll
      for (int i = 0; i < 2; ++i) {
        int d = w*16 + i*8 + (lane >> 3);
        int cb = (lane & 7) ^ (d & 7);
        gld16(VTg + vbase + (size_t)d*SEQ + s0 + 64 + cb*8, &Vsh[w*16 + i*8][0]);
      }
      __syncthreads();   // tile 1 staged
    }
    if (!(kt == 1 && w < 4)) {
      float rowf[4];
      #pragma unroll
      for (int reg = 0; reg < 4; ++reg)
        rowf[reg] = exp2f(l2g * (float)(16*w + 4*lg + reg - t0));

      #pragma unroll
      for (int ts = 0; ts < 4; ++ts) {
        f32x4 sacc = (f32x4){0.f,0.f,0.f,0.f};
        int trow = 16*ts + lr;
        #pragma unroll
        for (int ks = 0; ks < 4; ++ks) {
          int kbs = (4*ks + lg) ^ (trow & 7);
          bf16x8 kh8 = *(const bf16x8*)&Ksh[trow][kbs*8];
          sacc = __builtin_amdgcn_mfma_f32_16x16x32_bf16(qh[ks], kh8, sacc, 0, 0, 0);
        }
        float cf = colf * g16v[ts];
        #pragma unroll
        for (int reg = 0; reg < 4; ++reg) {
          int qloc = 4*lg + reg;
          int diff = (16*w + qloc) - (t0 + trow);
          float p = (diff >= 0) ? sacc[reg] * (rowf[reg] * cf) : 0.0f;
          int cb = (trow >> 3) ^ (qloc & 7);
          Ph[16*w + qloc][cb*8 + (trow & 7)] = (bf16_t)p;
        }
      }
      #pragma unroll
      for (int ks = 0; ks < 2; ++ks) {
        int prow = 16*w + lr;
        int pcb = (4*ks + lg) ^ (lr & 7);
        bf16x8 pah = *(const bf16x8*)&Ph[prow][pcb*8];
        #pragma unroll
        for (int sub = 0; sub < 8; ++sub) {
          int drow = 16*sub + lr;
          int vcb = (4*ks + lg) ^ (drow & 7);
          bf16x8 vh8 = *(const bf16x8*)&Vsh[drow][vcb*8];
          yacc[sub] = __builtin_amdgcn_mfma_f32_16x16x32_bf16(pah, vh8, yacc[sub], 0, 0, 0);
        }
      }
    }
  }

  // ---- fused groupnorm (bf16 out) ----
  float s1v[4] = {0.f,0.f,0.f,0.f}, s2v[4] = {0.f,0.f,0.f,0.f};
  #pragma unroll
  for (int sub = 0; sub < 8; ++sub)
    #pragma unroll
    for (int reg = 0; reg < 4; ++reg) {
      float v = yacc[sub][reg];
      s1v[reg] += v;
      s2v[reg] += v * v;
    }
  #pragma unroll
  for (int off = 8; off; off >>= 1)
    #pragma unroll
    for (int reg = 0; reg < 4; ++reg) {
      s1v[reg] += __shfl_xor(s1v[reg], off);
      s2v[reg] += __shfl_xor(s2v[reg], off);
    }
  float gwv[8], gbv[8];
  #pragma unroll
  for (int sub = 0; sub < 8; ++sub) {
    gwv[sub] = gw[hh*DH + 16*sub + lr];
    gbv[sub] = gb[hh*DH + 16*sub + lr];
  }
  int b = bh >> 3;
  #pragma unroll
  for (int reg = 0; reg < 4; ++reg) {
    float mean = s1v[reg] * (1.0f/128.0f);
    float var = s2v[reg] * (1.0f/128.0f) - mean*mean;
    float inv = rsqrtf(var + 1e-5f);
    int srow = s0 + 16*w + 4*lg + reg;
    bf16_t* op = Yn + (size_t)(b*SEQ + srow) * HD + hh*DH;
    #pragma unroll
    for (int sub = 0; sub < 8; ++sub)
      op[16*sub + lr] = (bf16_t)((yacc[sub][reg] - mean) * inv * gwv[sub] + gbv[sub]);
  }
}

// ---------------- plain-bf16 MFMA GEMM, 64x128 tile, 2 blocks/CU -----------
__global__ __launch_bounds__(256, 2) void k_gemm(
    const bf16_t* __restrict__ Ag, const bf16_t* __restrict__ Bg,
    const bf16_t* __restrict__ E,
    bf16_t* __restrict__ Oh, float* __restrict__ Of, int mode) {
  __shared__ bf16_t SA[2][64][64];
  __shared__ bf16_t SBB[2][128][64];
  int t = threadIdx.x;
  int lane = t & 63, w = t >> 6;          // 4 waves
  int lr = lane & 15, lg = lane >> 4;
  int wr = w >> 1, wc = w & 1;            // wave tile: 32(m) x 64(n)
  int bid = blockIdx.x;                   // 512 blocks
  int xcd = bid & 7, local = bid >> 3;
  int mp = xcd * 8 + (local >> 3);        // 64 m-panels, 8 contiguous per XCD
  int np = local & 7;                     // 8 n-panels
  int m0 = mp * 64, n0 = np * 128;

  const bf16_t* As = Ag + (size_t)m0 * HD;
  const bf16_t* Bs = Bg + (size_t)n0 * HD;

  f32x4 acc[2][4];
  #pragma unroll
  for (int i = 0; i < 2; ++i)
    #pragma unroll
    for (int j = 0; j < 4; ++j) acc[i][j] = (f32x4){0.f,0.f,0.f,0.f};

  int srow = lane >> 3, sch = lane & 7;

  {
    #pragma unroll
    for (int i = 0; i < 2; ++i) {
      int row = w*16 + i*8 + srow;
      int kc = (sch ^ (row & 7)) * 8;
      gld16(As + (size_t)row*HD + kc, &SA[0][w*16 + i*8][0]);
    }
    #pragma unroll
    for (int i = 0; i < 4; ++i) {
      int row = w*32 + i*8 + srow;
      int kc = (sch ^ (row & 7)) * 8;
      gld16(Bs + (size_t)row*HD + kc, &SBB[0][w*32 + i*8][0]);
    }
  }
  __syncthreads();

  int buf = 0;
  for (int kt = 0; kt < 16; ++kt) {
    if (kt + 1 < 16) {
      int k0 = (kt + 1) * 64;
      #pragma unroll
      for (int i = 0; i < 2; ++i) {
        int row = w*16 + i*8 + srow;
        int kc = (sch ^ (row & 7)) * 8;
        gld16(As + (size_t)row*HD + k0 + kc, &SA[buf^1][w*16 + i*8][0]);
      }
      #pragma unroll
      for (int i = 0; i < 4; ++i) {
        int row = w*32 + i*8 + srow;
        int kc = (sch ^ (row & 7)) * 8;
        gld16(Bs + (size_t)row*HD + k0 + kc, &SBB[buf^1][w*32 + i*8][0]);
      }
    }
    #pragma unroll
    for (int ks = 0; ks < 2; ++ks) {
      bf16x8 a_[2], b_[4];
      #pragma unroll
      for (int mf = 0; mf < 2; ++mf) {
        int row = wr*32 + mf*16 + lr;
        int ch = (lg + 4*ks) ^ (row & 7);
        a_[mf] = *(const bf16x8*)&SA[buf][row][ch*8];
      }
      #pragma unroll
      for (int nf = 0; nf < 4; ++nf) {
        int row = wc*64 + nf*16 + lr;
        int ch = (lg + 4*ks) ^ (row & 7);
        b_[nf] = *(const bf16x8*)&SBB[buf][row][ch*8];
      }
      #pragma unroll
      for (int mf = 0; mf < 2; ++mf)
        #pragma unroll
        for (int nf = 0; nf < 4; ++nf)
          acc[mf][nf] = __builtin_amdgcn_mfma_f32_16x16x32_bf16(a_[mf], b_[nf], acc[mf][nf], 0, 0, 0);
    }
    __syncthreads();
    buf ^= 1;
  }
  #pragma unroll
  for (int mf = 0; mf < 2; ++mf) {
    #pragma unroll
    for (int nf = 0; nf < 4; ++nf) {
      #pragma unroll
      for (int reg = 0; reg < 4; ++reg) {
        int m = m0 + wr*32 + mf*16 + 4*lg + reg;
        int n = n0 + wc*64 + nf*16 + lr;
        float g = acc[mf][nf][reg];
        size_t off = (size_t)m * HD + n;
        if (mode == 1) {
          float sg = 1.0f / (1.0f + expf(-g));
          Oh[off] = (bf16_t)(g * sg * (float)E[off]);
        } else {
          Of[off] = g;
        }
      }
    }
  }
}

extern "C" void kernel_launch(void* const* d_in, const int* in_sizes, int n_in,
                              void* d_out, int out_size, void* d_ws, size_t ws_size,
                              hipStream_t stream) {
  const float* X  = (const float*)d_in[0];
  const float* Wq = (const float*)d_in[1];
  const float* Wk = (const float*)d_in[2];
  const float* Wv = (const float*)d_in[3];
  const float* Wg = (const float*)d_in[4];
  const float* Wo = (const float*)d_in[5];
  const float* gw = (const float*)d_in[6];
  const float* gb = (const float*)d_in[7];
  float* out = (float*)d_out;
  float* ws = (float*)d_ws;

  // ws: tabs 2.1MB | Q K VT 3x8.4 | Yn 8.4 | DSt 8.4 | W ~4.8 | Xh 8.4 (~57MB)
  float* tabs = ws;
  bf16_t* Q   = (bf16_t*)(ws + 524288);
  bf16_t* K   = Q + 4194304;
  bf16_t* VT  = K + 4194304;
  bf16_t* Yn  = VT + 4194304;
  bf16_t* DSt = Yn + 4194304;
  bf16_t* Wqt = DSt + 4194304;
  bf16_t* Wkt = Wqt + 131072;
  bf16_t* Wvt = Wkt + 131072;
  bf16_t* Wgt = Wvt + 131072;
  bf16_t* Wot = Wgt + 1048576;
  bf16_t* Xh  = Wot + 1048576;
  bf16_t* A2  = Q;                 // Q dead after k_ret

  k_prep<<<dim3(608), dim3(256), 0, stream>>>(Wq, Wk, Wv, tabs, Wqt, Wkt, Wvt);
  k_qkvd<<<dim3(16, 8, 2), dim3(512), 0, stream>>>(X, tabs, Wqt, Wkt, Wvt,
                                                   Q, K, VT, Xh, DSt);
  k_ret<<<dim3(768), dim3(512), 0, stream>>>(Q, K, VT, DSt, gw, gb, Yn,
                                             Wg, Wo, Wgt, Wot);
  k_gemm<<<dim3(512), dim3(256), 0, stream>>>(Xh, Wgt, Yn, A2, nullptr, 1);
  k_gemm<<<dim3(512), dim3(256), 0, stream>>>(A2, Wot, nullptr, nullptr, out, 0);
}